// Round 5
// baseline (1071.892 us; speedup 1.0000x reference)
//
#include <hip/hip_runtime.h>

#define BB 512
#define TT 256

typedef __attribute__((ext_vector_type(8))) short bf16x8;
typedef __attribute__((ext_vector_type(4))) float f32x4;

__device__ __forceinline__ unsigned short f2b(float f) {
    union { float f; unsigned u; } v; v.f = f;
    unsigned r = v.u + 0x7FFFu + ((v.u >> 16) & 1u);  // round-to-nearest-even
    return (unsigned short)(r >> 16);
}
__device__ __forceinline__ float b2f(unsigned short h) {
    union { unsigned u; float f; } v; v.u = ((unsigned)h) << 16;
    return v.f;
}

// ---------------- fp32 -> bf16 convert (x input) ----------------
__global__ __launch_bounds__(256) void cvt_kernel(const float* __restrict__ x,
                                                  unsigned short* __restrict__ xb, int n4) {
    int i = blockIdx.x * 256 + threadIdx.x;
    if (i >= n4) return;
    float4 v = reinterpret_cast<const float4*>(x)[i];
    ushort4 o;
    o.x = f2b(v.x); o.y = f2b(v.y); o.z = f2b(v.z); o.w = f2b(v.w);
    reinterpret_cast<ushort4*>(xb)[i] = o;
}

// ---------------- input-projection GEMM (operand-swapped) ----------------
// D = W^T · x^T : A-frag = W^T (m = out-col), B-frag = x rows (n = batch-row).
// XP tile (s,t,ntg) at ((s*T+t)*(N/16)+ntg)*256, elem lane*4+reg, meaning
// (batch = lane&15, col = ntg*16 + (lane>>4)*4 + reg). Same products, same
// kc order as unswapped -> numerics unchanged.
template<int K, int N>
__global__ __launch_bounds__(256, 2) void gemm_xp(const unsigned short* __restrict__ A,
                                                  const float* __restrict__ W,
                                                  const float* __restrict__ bias,
                                                  unsigned short* __restrict__ XP) {
    constexpr int NT = N / 64;   // m-tiles per wave
    constexpr int KC = K / 32;   // k-chunks
    __shared__ unsigned short WT[N * K];
    const int tid = threadIdx.x;
    for (int idx = tid; idx < K * N; idx += 256) {
        int k = idx / N, n = idx % N;
        int ch = k >> 3;
        WT[n * K + (((ch ^ (n & 7)) << 3) | (k & 7))] = f2b(W[idx]);
    }
    __syncthreads();
    const int s   = blockIdx.x >> 6;
    const int t4  = blockIdx.x & 63;
    const int w   = tid >> 6;
    const int lane = tid & 63;
    const int l15 = lane & 15;
    const int quad = lane >> 4;

    f32x4 acc[4][NT];
#pragma unroll
    for (int mt = 0; mt < 4; ++mt)
#pragma unroll
        for (int nt = 0; nt < NT; ++nt) acc[mt][nt] = (f32x4)(0.0f);

#pragma unroll
    for (int kc = 0; kc < KC; ++kc) {
        bf16x8 bfr[NT];
        const int ch = kc * 4 + quad;
#pragma unroll
        for (int nt = 0; nt < NT; ++nt) {
            int n = w * (N / 4) + nt * 16 + l15;
            bfr[nt] = *reinterpret_cast<const bf16x8*>(&WT[n * K + ((ch ^ (n & 7)) << 3)]);
        }
#pragma unroll
        for (int mt = 0; mt < 4; ++mt) {
            int row = (s * 16 + l15) * TT + (t4 * 4 + mt);
            bf16x8 bf = *reinterpret_cast<const bf16x8*>(&A[(size_t)row * K + kc * 32 + quad * 8]);
#pragma unroll
            for (int nt = 0; nt < NT; ++nt)
                acc[mt][nt] = __builtin_amdgcn_mfma_f32_16x16x32_bf16(bfr[nt], bf, acc[mt][nt], 0, 0, 0);
        }
    }
#pragma unroll
    for (int mt = 0; mt < 4; ++mt) {
        int t = t4 * 4 + mt;
#pragma unroll
        for (int nt = 0; nt < NT; ++nt) {
            int ntg = w * NT + nt;
            float4 bv = reinterpret_cast<const float4*>(bias)[ntg * 4 + quad];
            size_t base = ((size_t)(s * TT + t) * (N / 16) + ntg) * 256;
            ushort4 o;
            o.x = f2b(acc[mt][nt][0] + bv.x);
            o.y = f2b(acc[mt][nt][1] + bv.y);
            o.z = f2b(acc[mt][nt][2] + bv.z);
            o.w = f2b(acc[mt][nt][3] + bv.w);
            *reinterpret_cast<ushort4*>(&XP[base + (size_t)lane * 4]) = o;
        }
    }
}

// ---------------- batch-partitioned recurrence (H <= 128) ----------------
// One 64-thread wave per block owns 16 batch rows and computes ALL H cols:
// h never leaves the wave -> NO barriers. Wh^T frags permanent in VGPRs.
// LDS = tiny per-wave staging (same-wave DS ops are in-order): epilogue
// packs h_t as ushort4 b64 writes, then b128 af reads + coalesced writeback.
template<int H>
__global__ __launch_bounds__(64, 1) void rec_bp(const unsigned short* __restrict__ XP,
                                                const float* __restrict__ Wh,
                                                unsigned short* __restrict__ Hout) {
    constexpr int KC  = H / 32;
    constexpr int MT  = H / 16;
    constexpr int HPP = H + 8;
    __shared__ unsigned short hs[16 * HPP];
    const int lane = threadIdx.x;
    const int s = blockIdx.x;          // batch slice 0..31
    const int l15 = lane & 15;
    const int quad = lane >> 4;

    // Wh^T A-fragments: wh[kc][mt] -> m = mt*16+l15, k = kc*32+quad*8+j
    bf16x8 wh[KC][MT];
#pragma unroll
    for (int kc = 0; kc < KC; ++kc)
#pragma unroll
        for (int mt = 0; mt < MT; ++mt) {
            int m = mt * 16 + l15;
#pragma unroll
            for (int j = 0; j < 8; ++j)
                wh[kc][mt][j] = (short)f2b(Wh[(kc * 32 + quad * 8 + j) * H + m]);
        }

    const unsigned short* XPs = XP + (size_t)s * TT * (H / 16) * 256;

    // xp prefetch (t=0)
    ushort4 xpr[MT], xpn[MT];
#pragma unroll
    for (int mt = 0; mt < MT; ++mt)
        xpr[mt] = reinterpret_cast<const ushort4*>(&XPs[(size_t)mt * 256])[lane];

    bf16x8 af[KC];   // h_{t-1} B-frags; h_{-1} = 0
#pragma unroll
    for (int kc = 0; kc < KC; ++kc) af[kc] = (bf16x8)(short)0;

#pragma unroll 1
    for (int t = 0; t < TT; ++t) {
        // prefetch xp(t+1)
        if (t + 1 < TT) {
#pragma unroll
            for (int mt = 0; mt < MT; ++mt)
                xpn[mt] = reinterpret_cast<const ushort4*>(
                    &XPs[((size_t)(t + 1) * MT + mt) * 256])[lane];
        }

        f32x4 acc[MT];
#pragma unroll
        for (int mt = 0; mt < MT; ++mt) acc[mt] = (f32x4)(0.0f);
#pragma unroll
        for (int kc = 0; kc < KC; ++kc)
#pragma unroll
            for (int mt = 0; mt < MT; ++mt)
                acc[mt] = __builtin_amdgcn_mfma_f32_16x16x32_bf16(wh[kc][mt], af[kc], acc[mt], 0, 0, 0);

        // epilogue: lane holds (batch=l15, cols mt*16+quad*4+reg) -> pack + b64 store
#pragma unroll
        for (int mt = 0; mt < MT; ++mt) {
            ushort4 o;
            o.x = f2b(fmaxf(acc[mt][0] + b2f(xpr[mt].x), 0.f));
            o.y = f2b(fmaxf(acc[mt][1] + b2f(xpr[mt].y), 0.f));
            o.z = f2b(fmaxf(acc[mt][2] + b2f(xpr[mt].z), 0.f));
            o.w = f2b(fmaxf(acc[mt][3] + b2f(xpr[mt].w), 0.f));
            *reinterpret_cast<ushort4*>(&hs[l15 * HPP + mt * 16 + quad * 4]) = o;
        }

        // af for t+1 (b128 reads; same-wave in-order DS guarantees RAW)
#pragma unroll
        for (int kc = 0; kc < KC; ++kc)
            af[kc] = *reinterpret_cast<const bf16x8*>(&hs[l15 * HPP + kc * 32 + quad * 8]);

        // coalesced global writeback of h_t
        constexpr int CHUNKS = 16 * H / 8;   // 16B chunks
#pragma unroll
        for (int ci = 0; ci < CHUNKS / 64; ++ci) {
            int idx = ci * 64 + lane;
            int row = idx / (H / 8);
            int off = (idx % (H / 8)) * 8;
            uint4 v = *reinterpret_cast<const uint4*>(&hs[row * HPP + off]);
            size_t g = ((size_t)(s * 16 + row) * TT + t) * H + off;
            *reinterpret_cast<uint4*>(&Hout[g]) = v;
        }

#pragma unroll
        for (int mt = 0; mt < MT; ++mt) xpr[mt] = xpn[mt];
    }
}

// ---------------- col-partitioned recurrence (H = 256) ----------------
// Wh too big for one wave's registers -> 4 waves split cols, h exchanged via
// LDS ping-pong. Operand-swapped: epilogue is 4 packed ds_write_b64 per wave
// (was 16 ds_write_b16). Raw lgkm-only barrier per step.
template<int H>
__global__ __launch_bounds__(256, 1) void rec_cp(const unsigned short* __restrict__ XP,
                                                 const float* __restrict__ Wh,
                                                 unsigned short* __restrict__ Hout) {
    constexpr int KC = H / 32;
    constexpr int MT = H / 64;          // m-tiles per wave (4 waves)
    constexpr int HP = H + 8;
    __shared__ unsigned short hbuf[2][16 * HP];
    const int tid = threadIdx.x;
    const int s = blockIdx.x;
    const int w = tid >> 6;
    const int lane = tid & 63;
    const int l15 = lane & 15;
    const int quad = lane >> 4;
    const int colbase = w * (H / 4);

    bf16x8 wh[KC][MT];
#pragma unroll
    for (int kc = 0; kc < KC; ++kc)
#pragma unroll
        for (int mt = 0; mt < MT; ++mt) {
            int m = colbase + mt * 16 + l15;
#pragma unroll
            for (int j = 0; j < 8; ++j)
                wh[kc][mt][j] = (short)f2b(Wh[(kc * 32 + quad * 8 + j) * H + m]);
        }

    for (int i = tid; i < 16 * HP; i += 256) hbuf[0][i] = 0;
    __syncthreads();

    const unsigned short* XPs = XP + (size_t)s * TT * (H / 16) * 256;

    ushort4 xpr[MT], xpn[MT];
#pragma unroll
    for (int mt = 0; mt < MT; ++mt)
        xpr[mt] = reinterpret_cast<const ushort4*>(&XPs[(size_t)(w * MT + mt) * 256])[lane];

#pragma unroll 1
    for (int t = 0; t < TT; ++t) {
        const unsigned short* hr = hbuf[t & 1];
        unsigned short* hw = hbuf[(t + 1) & 1];

        bf16x8 af[KC];
#pragma unroll
        for (int kc = 0; kc < KC; ++kc)
            af[kc] = *reinterpret_cast<const bf16x8*>(&hr[l15 * HP + kc * 32 + quad * 8]);

        if (t + 1 < TT) {
#pragma unroll
            for (int mt = 0; mt < MT; ++mt)
                xpn[mt] = reinterpret_cast<const ushort4*>(
                    &XPs[((size_t)(t + 1) * (H / 16) + (w * MT + mt)) * 256])[lane];
        }

        f32x4 acc[MT];
#pragma unroll
        for (int mt = 0; mt < MT; ++mt) acc[mt] = (f32x4)(0.0f);
#pragma unroll
        for (int kc = 0; kc < KC; ++kc)
#pragma unroll
            for (int mt = 0; mt < MT; ++mt)
                acc[mt] = __builtin_amdgcn_mfma_f32_16x16x32_bf16(wh[kc][mt], af[kc], acc[mt], 0, 0, 0);

#pragma unroll
        for (int mt = 0; mt < MT; ++mt) {
            ushort4 o;
            o.x = f2b(fmaxf(acc[mt][0] + b2f(xpr[mt].x), 0.f));
            o.y = f2b(fmaxf(acc[mt][1] + b2f(xpr[mt].y), 0.f));
            o.z = f2b(fmaxf(acc[mt][2] + b2f(xpr[mt].z), 0.f));
            o.w = f2b(fmaxf(acc[mt][3] + b2f(xpr[mt].w), 0.f));
            *reinterpret_cast<ushort4*>(&hw[l15 * HP + colbase + mt * 16 + quad * 4]) = o;
        }
        // lgkm-only drain + barrier (global ops stay in flight)
        asm volatile("s_waitcnt lgkmcnt(0)\n\ts_barrier" ::: "memory");

        // coalesced global writeback of h_t
        constexpr int CHUNKS = 16 * H / 8;
        for (int ci = tid; ci < CHUNKS; ci += 256) {
            int row = ci / (H / 8);
            int off = (ci % (H / 8)) * 8;
            uint4 v = *reinterpret_cast<const uint4*>(&hw[row * HP + off]);
            size_t g = ((size_t)(s * 16 + row) * TT + t) * H + off;
            *reinterpret_cast<uint4*>(&Hout[g]) = v;
        }

#pragma unroll
        for (int mt = 0; mt < MT; ++mt) xpr[mt] = xpn[mt];
    }
}

// ---------------- final dense: out[b] = flat[b,:] . Wd + bd ----------------
__global__ __launch_bounds__(256) void dense_kernel(const unsigned short* __restrict__ Hb,
                                                    const float* __restrict__ Wd,
                                                    const float* __restrict__ bd,
                                                    float* __restrict__ out) {
    __shared__ float red[256];
    const int b = blockIdx.x;
    const int tid = threadIdx.x;
    const unsigned short* row = Hb + (size_t)b * (TT * 64);
    float acc = 0.f;
    for (int j = tid; j < TT * 64; j += 256)
        acc += b2f(row[j]) * Wd[j];
    red[tid] = acc;
    __syncthreads();
    for (int s2 = 128; s2 > 0; s2 >>= 1) {
        if (tid < s2) red[tid] += red[tid + s2];
        __syncthreads();
    }
    if (tid == 0) out[b] = red[0] + bd[0];
}

extern "C" void kernel_launch(void* const* d_in, const int* in_sizes, int n_in,
                              void* d_out, int out_size, void* d_ws, size_t ws_size,
                              hipStream_t stream) {
    (void)in_sizes; (void)n_in; (void)out_size; (void)ws_size;
    const float* x   = (const float*)d_in[0];
    const float* Wx1 = (const float*)d_in[1];
    const float* Wh1 = (const float*)d_in[2];
    const float* b1  = (const float*)d_in[3];
    const float* Wx2 = (const float*)d_in[4];
    const float* Wh2 = (const float*)d_in[5];
    const float* b2  = (const float*)d_in[6];
    const float* Wx3 = (const float*)d_in[7];
    const float* Wh3 = (const float*)d_in[8];
    const float* b3  = (const float*)d_in[9];
    const float* Wx4 = (const float*)d_in[10];
    const float* Wh4 = (const float*)d_in[11];
    const float* b4  = (const float*)d_in[12];
    const float* Wd  = (const float*)d_in[13];
    const float* bd  = (const float*)d_in[14];
    float* out = (float*)d_out;

    char* ws = (char*)d_ws;
    unsigned short* xb = (unsigned short*)(ws);
    unsigned short* XP = (unsigned short*)(ws + 16777216);
    unsigned short* H0 = (unsigned short*)(ws + 16777216 + 67108864);
    unsigned short* H1 = (unsigned short*)(ws + 16777216 + 2 * 67108864);

    cvt_kernel<<<8192, 256, 0, stream>>>(x, xb, BB * TT * 64 / 4);

    gemm_xp<64, 128><<<2048, 256, 0, stream>>>(xb, Wx1, b1, XP);
    rec_bp<128><<<32, 64, 0, stream>>>(XP, Wh1, H0);

    gemm_xp<128, 256><<<2048, 256, 0, stream>>>(H0, Wx2, b2, XP);
    rec_cp<256><<<32, 256, 0, stream>>>(XP, Wh2, H1);

    gemm_xp<256, 128><<<2048, 256, 0, stream>>>(H1, Wx3, b3, XP);
    rec_bp<128><<<32, 64, 0, stream>>>(XP, Wh3, H0);

    gemm_xp<128, 64><<<2048, 256, 0, stream>>>(H0, Wx4, b4, XP);
    rec_bp<64><<<32, 64, 0, stream>>>(XP, Wh4, H1);

    dense_kernel<<<512, 256, 0, stream>>>(H1, Wd, bd, out);
}

// Round 6
// 893.691 us; speedup vs baseline: 1.1994x; 1.1994x over previous
//
#include <hip/hip_runtime.h>
#include <hip/hip_bf16.h>

#define BB 512
#define TT 256

typedef __attribute__((ext_vector_type(8))) short bf16x8;
typedef __attribute__((ext_vector_type(4))) float f32x4;

__device__ __forceinline__ unsigned short f2b(float f) {
    union { float f; unsigned u; } v; v.f = f;
    unsigned r = v.u + 0x7FFFu + ((v.u >> 16) & 1u);
    return (unsigned short)(r >> 16);
}
__device__ __forceinline__ float b2f(unsigned short h) {
    union { unsigned u; float f; } v; v.u = ((unsigned)h) << 16;
    return v.f;
}
// packed f32x2 -> bf16x2 (v_cvt_pk_bf16_f32, RNE — bit-compatible with f2b)
__device__ __forceinline__ ushort2 pk2(float a, float b) {
    __hip_bfloat162 h = __float22bfloat162_rn(float2{a, b});
    union { __hip_bfloat162 h; ushort2 u; } v; v.h = h; return v.u;
}

// ---------------- fp32 -> bf16 convert (x input, linear layout) ----------------
__global__ __launch_bounds__(256) void cvt_kernel(const float* __restrict__ x,
                                                  unsigned short* __restrict__ xb, int n4) {
    int i = blockIdx.x * 256 + threadIdx.x;
    if (i >= n4) return;
    float4 v = reinterpret_cast<const float4*>(x)[i];
    ushort2 lo = pk2(v.x, v.y), hi = pk2(v.z, v.w);
    ushort4 o; o.x = lo.x; o.y = lo.y; o.z = hi.x; o.w = hi.y;
    reinterpret_cast<ushort4*>(xb)[i] = o;
}

// ---------------- input-projection GEMM (operand-swapped) ----------------
// D = W^T · x^T. XP out tile (s,t,ntg) at ((s*TT+t)*(N/16)+ntg)*256, elem
// lane*4+reg = (batch l15, col ntg*16+quad*4+reg).
// TILED=0: A is linear [b][t][k] bf16 (layer-1 x). TILED=1: A is tile-layout
// (previous rec output): fragment = two b64 loads 128B apart, coalesced.
template<int K, int N, int TILED>
__global__ __launch_bounds__(256, 2) void gemm_xp(const unsigned short* __restrict__ A,
                                                  const float* __restrict__ W,
                                                  const float* __restrict__ bias,
                                                  unsigned short* __restrict__ XP) {
    constexpr int NT = N / 64;
    constexpr int KC = K / 32;
    __shared__ unsigned short WT[N * K];
    const int tid = threadIdx.x;
    for (int idx = tid; idx < K * N; idx += 256) {
        int k = idx / N, n = idx % N;
        int ch = k >> 3;
        WT[n * K + (((ch ^ (n & 7)) << 3) | (k & 7))] = f2b(W[idx]);
    }
    __syncthreads();
    const int s   = blockIdx.x >> 6;
    const int t4  = blockIdx.x & 63;
    const int w   = tid >> 6;
    const int lane = tid & 63;
    const int l15 = lane & 15;
    const int quad = lane >> 4;

    f32x4 acc[4][NT];
#pragma unroll
    for (int mt = 0; mt < 4; ++mt)
#pragma unroll
        for (int nt = 0; nt < NT; ++nt) acc[mt][nt] = (f32x4)(0.0f);

#pragma unroll
    for (int kc = 0; kc < KC; ++kc) {
        bf16x8 bfr[NT];
        const int ch = kc * 4 + quad;
#pragma unroll
        for (int nt = 0; nt < NT; ++nt) {
            int n = w * (N / 4) + nt * 16 + l15;
            bfr[nt] = *reinterpret_cast<const bf16x8*>(&WT[n * K + ((ch ^ (n & 7)) << 3)]);
        }
#pragma unroll
        for (int mt = 0; mt < 4; ++mt) {
            int t = t4 * 4 + mt;
            bf16x8 bf;
            if (TILED) {
                const unsigned short* tp =
                    &A[(((size_t)(s * TT + t) * (K / 16)) + kc * 2 + (quad >> 1)) * 256];
                int e = ((quad & 1) * 32 + l15) * 4;
                union { ushort4 u4[2]; bf16x8 v; } u;
                u.u4[0] = *reinterpret_cast<const ushort4*>(&tp[e]);
                u.u4[1] = *reinterpret_cast<const ushort4*>(&tp[e + 64]);
                bf = u.v;
            } else {
                int row = (s * 16 + l15) * TT + t;
                bf = *reinterpret_cast<const bf16x8*>(&A[(size_t)row * K + kc * 32 + quad * 8]);
            }
#pragma unroll
            for (int nt = 0; nt < NT; ++nt)
                acc[mt][nt] = __builtin_amdgcn_mfma_f32_16x16x32_bf16(bfr[nt], bf, acc[mt][nt], 0, 0, 0);
        }
    }
#pragma unroll
    for (int mt = 0; mt < 4; ++mt) {
        int t = t4 * 4 + mt;
#pragma unroll
        for (int nt = 0; nt < NT; ++nt) {
            int ntg = w * NT + nt;
            float4 bv = reinterpret_cast<const float4*>(bias)[ntg * 4 + quad];
            size_t base = ((size_t)(s * TT + t) * (N / 16) + ntg) * 256;
            ushort2 lo = pk2(acc[mt][nt][0] + bv.x, acc[mt][nt][1] + bv.y);
            ushort2 hi = pk2(acc[mt][nt][2] + bv.z, acc[mt][nt][3] + bv.w);
            ushort4 o; o.x = lo.x; o.y = lo.y; o.z = hi.x; o.w = hi.y;
            *reinterpret_cast<ushort4*>(&XP[base + (size_t)lane * 4]) = o;
        }
    }
}

// ---------------- recurrence: h_t = relu(xp_t + h_{t-1} @ Wh) ----------------
// Col-partitioned, 4 waves, operand-swapped (A = Wh^T in VGPRs, B = h from
// LDS ping-pong). acc initialized with xp (saves the adds). h_t leaves the
// epilogue registers twice: packed b64 -> LDS (next step's B-frags) and
// ushort4 -> global in TILE layout (8B/lane, fully coalesced) — no LDS
// re-read, no writeback address math. Raw lgkm-only barrier per step.
template<int H>
__global__ __launch_bounds__(256, 1) void rec_cp(const unsigned short* __restrict__ XP,
                                                 const float* __restrict__ Wh,
                                                 unsigned short* __restrict__ Hout) {
    constexpr int KC = H / 32;
    constexpr int MT = H / 64;
    constexpr int HP = H + 8;
    __shared__ unsigned short hbuf[2][16 * HP];
    const int tid = threadIdx.x;
    const int s = blockIdx.x;
    const int w = tid >> 6;
    const int lane = tid & 63;
    const int l15 = lane & 15;
    const int quad = lane >> 4;
    const int colbase = w * (H / 4);

    bf16x8 wh[KC][MT];
#pragma unroll
    for (int kc = 0; kc < KC; ++kc)
#pragma unroll
        for (int mt = 0; mt < MT; ++mt) {
            int m = colbase + mt * 16 + l15;
#pragma unroll
            for (int j = 0; j < 8; ++j)
                wh[kc][mt][j] = (short)f2b(Wh[(kc * 32 + quad * 8 + j) * H + m]);
        }

    for (int i = tid; i < 16 * HP; i += 256) hbuf[0][i] = 0;
    __syncthreads();

    const unsigned short* XPs = XP + (size_t)s * TT * (H / 16) * 256;

    ushort4 xpr[MT], xpn[MT];
#pragma unroll
    for (int mt = 0; mt < MT; ++mt)
        xpr[mt] = reinterpret_cast<const ushort4*>(&XPs[(size_t)(w * MT + mt) * 256])[lane];

#pragma unroll 1
    for (int t = 0; t < TT; ++t) {
        const unsigned short* hr = hbuf[t & 1];
        unsigned short* hw = hbuf[(t + 1) & 1];

        bf16x8 af[KC];
#pragma unroll
        for (int kc = 0; kc < KC; ++kc)
            af[kc] = *reinterpret_cast<const bf16x8*>(&hr[l15 * HP + kc * 32 + quad * 8]);

        if (t + 1 < TT) {
#pragma unroll
            for (int mt = 0; mt < MT; ++mt)
                xpn[mt] = reinterpret_cast<const ushort4*>(
                    &XPs[((size_t)(t + 1) * (H / 16) + (w * MT + mt)) * 256])[lane];
        }

        f32x4 acc[MT];
#pragma unroll
        for (int mt = 0; mt < MT; ++mt) {
            acc[mt][0] = b2f(xpr[mt].x);
            acc[mt][1] = b2f(xpr[mt].y);
            acc[mt][2] = b2f(xpr[mt].z);
            acc[mt][3] = b2f(xpr[mt].w);
        }
#pragma unroll
        for (int kc = 0; kc < KC; ++kc)
#pragma unroll
            for (int mt = 0; mt < MT; ++mt)
                acc[mt] = __builtin_amdgcn_mfma_f32_16x16x32_bf16(wh[kc][mt], af[kc], acc[mt], 0, 0, 0);

#pragma unroll
        for (int mt = 0; mt < MT; ++mt) {
            ushort2 lo = pk2(fmaxf(acc[mt][0], 0.f), fmaxf(acc[mt][1], 0.f));
            ushort2 hi = pk2(fmaxf(acc[mt][2], 0.f), fmaxf(acc[mt][3], 0.f));
            ushort4 o; o.x = lo.x; o.y = lo.y; o.z = hi.x; o.w = hi.y;
            // next step's h (LDS ping-pong)
            *reinterpret_cast<ushort4*>(&hw[l15 * HP + colbase + mt * 16 + quad * 4]) = o;
            // global h_t in tile layout — straight from registers, coalesced
            size_t gb = (((size_t)(s * TT + t)) * (H / 16) + w * MT + mt) * 256;
            *reinterpret_cast<ushort4*>(&Hout[gb + (size_t)lane * 4]) = o;
        }
        // lgkm-only drain + barrier: cross-wave deps are LDS-only; global
        // XP loads / Hout stores stay in flight across steps.
        asm volatile("s_waitcnt lgkmcnt(0)\n\ts_barrier" ::: "memory");

#pragma unroll
        for (int mt = 0; mt < MT; ++mt) xpr[mt] = xpn[mt];
    }
}

// ---------------- final dense: out[b] = flat[b,:] . Wd + bd ----------------
// H1 is tile-layout (H=64): block per batch-slice s; thread tid <-> tile elem
// tid = (q4*16+l15)*4+r, i.e. (b = s*16+l15, c = q4*4+r). Coalesced reads.
__global__ __launch_bounds__(256) void dense_kernel(const unsigned short* __restrict__ Ht,
                                                    const float* __restrict__ Wd,
                                                    const float* __restrict__ bd,
                                                    float* __restrict__ out) {
    __shared__ float red[16][17];
    const int s = blockIdx.x;
    const int tid = threadIdx.x;
    const int q4 = tid >> 6, l15 = (tid >> 2) & 15, r = tid & 3;
    const int c = q4 * 4 + r;
    float acc = 0.f;
    for (int t = 0; t < TT; ++t) {
        const unsigned short* base = &Ht[((size_t)(s * TT + t) * 4) * 256];
#pragma unroll
        for (int kt = 0; kt < 4; ++kt)
            acc += b2f(base[kt * 256 + tid]) * Wd[t * 64 + kt * 16 + c];
    }
    red[l15][q4 * 4 + r] = acc;
    __syncthreads();
    if (tid < 16) {
        float sum = 0.f;
#pragma unroll
        for (int j = 0; j < 16; ++j) sum += red[tid][j];
        out[s * 16 + tid] = sum + bd[0];
    }
}

extern "C" void kernel_launch(void* const* d_in, const int* in_sizes, int n_in,
                              void* d_out, int out_size, void* d_ws, size_t ws_size,
                              hipStream_t stream) {
    (void)in_sizes; (void)n_in; (void)out_size; (void)ws_size;
    const float* x   = (const float*)d_in[0];
    const float* Wx1 = (const float*)d_in[1];
    const float* Wh1 = (const float*)d_in[2];
    const float* b1  = (const float*)d_in[3];
    const float* Wx2 = (const float*)d_in[4];
    const float* Wh2 = (const float*)d_in[5];
    const float* b2  = (const float*)d_in[6];
    const float* Wx3 = (const float*)d_in[7];
    const float* Wh3 = (const float*)d_in[8];
    const float* b3  = (const float*)d_in[9];
    const float* Wx4 = (const float*)d_in[10];
    const float* Wh4 = (const float*)d_in[11];
    const float* b4  = (const float*)d_in[12];
    const float* Wd  = (const float*)d_in[13];
    const float* bd  = (const float*)d_in[14];
    float* out = (float*)d_out;

    char* ws = (char*)d_ws;
    unsigned short* xb = (unsigned short*)(ws);
    unsigned short* XP = (unsigned short*)(ws + 16777216);
    unsigned short* H0 = (unsigned short*)(ws + 16777216 + 67108864);
    unsigned short* H1 = (unsigned short*)(ws + 16777216 + 2 * 67108864);

    cvt_kernel<<<8192, 256, 0, stream>>>(x, xb, BB * TT * 64 / 4);

    gemm_xp<64, 128, 0><<<2048, 256, 0, stream>>>(xb, Wx1, b1, XP);
    rec_cp<128><<<32, 256, 0, stream>>>(XP, Wh1, H0);

    gemm_xp<128, 256, 1><<<2048, 256, 0, stream>>>(H0, Wx2, b2, XP);
    rec_cp<256><<<32, 256, 0, stream>>>(XP, Wh2, H1);

    gemm_xp<256, 128, 1><<<2048, 256, 0, stream>>>(H1, Wx3, b3, XP);
    rec_cp<128><<<32, 256, 0, stream>>>(XP, Wh3, H0);

    gemm_xp<128, 64, 1><<<2048, 256, 0, stream>>>(H0, Wx4, b4, XP);
    rec_cp<64><<<32, 256, 0, stream>>>(XP, Wh4, H1);

    dense_kernel<<<32, 256, 0, stream>>>(H1, Wd, bd, out);
}

// Round 7
// 890.325 us; speedup vs baseline: 1.2039x; 1.0038x over previous
//
#include <hip/hip_runtime.h>
#include <hip/hip_bf16.h>

#define BB 512
#define TT 256

typedef __attribute__((ext_vector_type(8))) short bf16x8;
typedef __attribute__((ext_vector_type(4))) float f32x4;

__device__ __forceinline__ unsigned short f2b(float f) {
    union { float f; unsigned u; } v; v.f = f;
    unsigned r = v.u + 0x7FFFu + ((v.u >> 16) & 1u);
    return (unsigned short)(r >> 16);
}
__device__ __forceinline__ float b2f(unsigned short h) {
    union { unsigned u; float f; } v; v.u = ((unsigned)h) << 16;
    return v.f;
}
// packed f32x2 -> bf16x2 (v_cvt_pk_bf16_f32, RNE — bit-compatible with f2b)
__device__ __forceinline__ ushort2 pk2(float a, float b) {
    __hip_bfloat162 h = __float22bfloat162_rn(float2{a, b});
    union { __hip_bfloat162 h; ushort2 u; } v; v.h = h; return v.u;
}

// ---------------- fp32 -> bf16 convert (x input, linear layout) ----------------
__global__ __launch_bounds__(256) void cvt_kernel(const float* __restrict__ x,
                                                  unsigned short* __restrict__ xb, int n4) {
    int i = blockIdx.x * 256 + threadIdx.x;
    if (i >= n4) return;
    float4 v = reinterpret_cast<const float4*>(x)[i];
    ushort2 lo = pk2(v.x, v.y), hi = pk2(v.z, v.w);
    ushort4 o; o.x = lo.x; o.y = lo.y; o.z = hi.x; o.w = hi.y;
    reinterpret_cast<ushort4*>(xb)[i] = o;
}

// ---------------- input-projection GEMM (operand-swapped) ----------------
// D = W^T · x^T. XP out tile (s,t,ntg) at ((s*TT+t)*(N/16)+ntg)*256, elem
// lane*4+reg = (batch l15, col ntg*16+quad*4+reg).
// TILED=0: A is linear [b][t][k] bf16 (layer-1 x). TILED=1: A is tile-layout
// (previous rec output): fragment = two b64 loads 128B apart, coalesced.
template<int K, int N, int TILED>
__global__ __launch_bounds__(256, 2) void gemm_xp(const unsigned short* __restrict__ A,
                                                  const float* __restrict__ W,
                                                  const float* __restrict__ bias,
                                                  unsigned short* __restrict__ XP) {
    constexpr int NT = N / 64;
    constexpr int KC = K / 32;
    __shared__ unsigned short WT[N * K];
    const int tid = threadIdx.x;
    for (int idx = tid; idx < K * N; idx += 256) {
        int k = idx / N, n = idx % N;
        int ch = k >> 3;
        WT[n * K + (((ch ^ (n & 7)) << 3) | (k & 7))] = f2b(W[idx]);
    }
    __syncthreads();
    const int s   = blockIdx.x >> 6;
    const int t4  = blockIdx.x & 63;
    const int w   = tid >> 6;
    const int lane = tid & 63;
    const int l15 = lane & 15;
    const int quad = lane >> 4;

    f32x4 acc[4][NT];
#pragma unroll
    for (int mt = 0; mt < 4; ++mt)
#pragma unroll
        for (int nt = 0; nt < NT; ++nt) acc[mt][nt] = (f32x4)(0.0f);

#pragma unroll
    for (int kc = 0; kc < KC; ++kc) {
        bf16x8 bfr[NT];
        const int ch = kc * 4 + quad;
#pragma unroll
        for (int nt = 0; nt < NT; ++nt) {
            int n = w * (N / 4) + nt * 16 + l15;
            bfr[nt] = *reinterpret_cast<const bf16x8*>(&WT[n * K + ((ch ^ (n & 7)) << 3)]);
        }
#pragma unroll
        for (int mt = 0; mt < 4; ++mt) {
            int t = t4 * 4 + mt;
            bf16x8 bf;
            if (TILED) {
                const unsigned short* tp =
                    &A[(((size_t)(s * TT + t) * (K / 16)) + kc * 2 + (quad >> 1)) * 256];
                int e = ((quad & 1) * 32 + l15) * 4;
                union { ushort4 u4[2]; bf16x8 v; } u;
                u.u4[0] = *reinterpret_cast<const ushort4*>(&tp[e]);
                u.u4[1] = *reinterpret_cast<const ushort4*>(&tp[e + 64]);
                bf = u.v;
            } else {
                int row = (s * 16 + l15) * TT + t;
                bf = *reinterpret_cast<const bf16x8*>(&A[(size_t)row * K + kc * 32 + quad * 8]);
            }
#pragma unroll
            for (int nt = 0; nt < NT; ++nt)
                acc[mt][nt] = __builtin_amdgcn_mfma_f32_16x16x32_bf16(bfr[nt], bf, acc[mt][nt], 0, 0, 0);
        }
    }
#pragma unroll
    for (int mt = 0; mt < 4; ++mt) {
        int t = t4 * 4 + mt;
#pragma unroll
        for (int nt = 0; nt < NT; ++nt) {
            int ntg = w * NT + nt;
            float4 bv = reinterpret_cast<const float4*>(bias)[ntg * 4 + quad];
            size_t base = ((size_t)(s * TT + t) * (N / 16) + ntg) * 256;
            ushort2 lo = pk2(acc[mt][nt][0] + bv.x, acc[mt][nt][1] + bv.y);
            ushort2 hi = pk2(acc[mt][nt][2] + bv.z, acc[mt][nt][3] + bv.w);
            ushort4 o; o.x = lo.x; o.y = lo.y; o.z = hi.x; o.w = hi.y;
            *reinterpret_cast<ushort4*>(&XP[base + (size_t)lane * 4]) = o;
        }
    }
}

// ---------------- recurrence: h_t = relu(xp_t + h_{t-1} @ Wh) ----------------
// Col-partitioned, 4 waves, operand-swapped (A = Wh^T in VGPRs, B = h from
// LDS ping-pong). acc initialized with xp. h_t leaves the epilogue registers
// twice: packed b64 -> LDS and ushort4 -> global in tile layout.
// Barrier = __builtin_amdgcn_s_waitcnt(lgkm-only) + s_barrier builtins — NO
// inline-asm memory clobber, so the backend inserts no vmcnt(0) drain: global
// XP loads and Hout store-acks stay in flight across steps.
template<int H>
__global__ __launch_bounds__(256, 1) void rec_cp(const unsigned short* __restrict__ XP,
                                                 const float* __restrict__ Wh,
                                                 unsigned short* __restrict__ Hout) {
    constexpr int KC = H / 32;
    constexpr int MT = H / 64;
    constexpr int HP = H + 8;
    __shared__ unsigned short hbuf[2][16 * HP];
    const int tid = threadIdx.x;
    const int s = blockIdx.x;
    const int w = tid >> 6;
    const int lane = tid & 63;
    const int l15 = lane & 15;
    const int quad = lane >> 4;
    const int colbase = w * (H / 4);

    bf16x8 wh[KC][MT];
#pragma unroll
    for (int kc = 0; kc < KC; ++kc)
#pragma unroll
        for (int mt = 0; mt < MT; ++mt) {
            int m = colbase + mt * 16 + l15;
#pragma unroll
            for (int j = 0; j < 8; ++j)
                wh[kc][mt][j] = (short)f2b(Wh[(kc * 32 + quad * 8 + j) * H + m]);
        }

    for (int i = tid; i < 16 * HP; i += 256) hbuf[0][i] = 0;
    __syncthreads();

    const unsigned short* XPs = XP + (size_t)s * TT * (H / 16) * 256;

    ushort4 xpr[MT], xpn[MT];
#pragma unroll
    for (int mt = 0; mt < MT; ++mt)
        xpr[mt] = reinterpret_cast<const ushort4*>(&XPs[(size_t)(w * MT + mt) * 256])[lane];

#pragma unroll 1
    for (int t = 0; t < TT; ++t) {
        const unsigned short* hr = hbuf[t & 1];
        unsigned short* hw = hbuf[(t + 1) & 1];

        bf16x8 af[KC];
#pragma unroll
        for (int kc = 0; kc < KC; ++kc)
            af[kc] = *reinterpret_cast<const bf16x8*>(&hr[l15 * HP + kc * 32 + quad * 8]);

        if (t + 1 < TT) {
#pragma unroll
            for (int mt = 0; mt < MT; ++mt)
                xpn[mt] = reinterpret_cast<const ushort4*>(
                    &XPs[((size_t)(t + 1) * (H / 16) + (w * MT + mt)) * 256])[lane];
        }

        f32x4 acc[MT];
#pragma unroll
        for (int mt = 0; mt < MT; ++mt) {
            acc[mt][0] = b2f(xpr[mt].x);
            acc[mt][1] = b2f(xpr[mt].y);
            acc[mt][2] = b2f(xpr[mt].z);
            acc[mt][3] = b2f(xpr[mt].w);
        }
#pragma unroll
        for (int kc = 0; kc < KC; ++kc)
#pragma unroll
            for (int mt = 0; mt < MT; ++mt)
                acc[mt] = __builtin_amdgcn_mfma_f32_16x16x32_bf16(wh[kc][mt], af[kc], acc[mt], 0, 0, 0);

#pragma unroll
        for (int mt = 0; mt < MT; ++mt) {
            ushort2 lo = pk2(fmaxf(acc[mt][0], 0.f), fmaxf(acc[mt][1], 0.f));
            ushort2 hi = pk2(fmaxf(acc[mt][2], 0.f), fmaxf(acc[mt][3], 0.f));
            ushort4 o; o.x = lo.x; o.y = lo.y; o.z = hi.x; o.w = hi.y;
            // next step's h (LDS ping-pong)
            *reinterpret_cast<ushort4*>(&hw[l15 * HP + colbase + mt * 16 + quad * 4]) = o;
            // global h_t in tile layout — straight from registers, coalesced
            size_t gb = (((size_t)(s * TT + t)) * (H / 16) + w * MT + mt) * 256;
            *reinterpret_cast<ushort4*>(&Hout[gb + (size_t)lane * 4]) = o;
        }
        // lgkm-only wait (vmcnt=63, expcnt=7 untouched: imm 0xC07F) + barrier.
        // Builtins, not inline asm: no "memory" clobber, so no backend-inserted
        // vmcnt(0) drain — global loads/stores remain in flight across steps.
        __builtin_amdgcn_s_waitcnt(0xC07F);
        __builtin_amdgcn_s_barrier();

#pragma unroll
        for (int mt = 0; mt < MT; ++mt) xpr[mt] = xpn[mt];
    }
}

// ---------------- final dense: out[b] = flat[b,:] . Wd + bd ----------------
// H1 is tile-layout (H=64): block per batch-slice s; thread tid <-> tile elem
// tid = (q4*16+l15)*4+r, i.e. (b = s*16+l15, c = q4*4+r). Coalesced reads.
__global__ __launch_bounds__(256) void dense_kernel(const unsigned short* __restrict__ Ht,
                                                    const float* __restrict__ Wd,
                                                    const float* __restrict__ bd,
                                                    float* __restrict__ out) {
    __shared__ float red[16][17];
    const int s = blockIdx.x;
    const int tid = threadIdx.x;
    const int q4 = tid >> 6, l15 = (tid >> 2) & 15, r = tid & 3;
    const int c = q4 * 4 + r;
    float acc = 0.f;
    for (int t = 0; t < TT; ++t) {
        const unsigned short* base = &Ht[((size_t)(s * TT + t) * 4) * 256];
#pragma unroll
        for (int kt = 0; kt < 4; ++kt)
            acc += b2f(base[kt * 256 + tid]) * Wd[t * 64 + kt * 16 + c];
    }
    red[l15][q4 * 4 + r] = acc;
    __syncthreads();
    if (tid < 16) {
        float sum = 0.f;
#pragma unroll
        for (int j = 0; j < 16; ++j) sum += red[tid][j];
        out[s * 16 + tid] = sum + bd[0];
    }
}

extern "C" void kernel_launch(void* const* d_in, const int* in_sizes, int n_in,
                              void* d_out, int out_size, void* d_ws, size_t ws_size,
                              hipStream_t stream) {
    (void)in_sizes; (void)n_in; (void)out_size; (void)ws_size;
    const float* x   = (const float*)d_in[0];
    const float* Wx1 = (const float*)d_in[1];
    const float* Wh1 = (const float*)d_in[2];
    const float* b1  = (const float*)d_in[3];
    const float* Wx2 = (const float*)d_in[4];
    const float* Wh2 = (const float*)d_in[5];
    const float* b2  = (const float*)d_in[6];
    const float* Wx3 = (const float*)d_in[7];
    const float* Wh3 = (const float*)d_in[8];
    const float* b3  = (const float*)d_in[9];
    const float* Wx4 = (const float*)d_in[10];
    const float* Wh4 = (const float*)d_in[11];
    const float* b4  = (const float*)d_in[12];
    const float* Wd  = (const float*)d_in[13];
    const float* bd  = (const float*)d_in[14];
    float* out = (float*)d_out;

    char* ws = (char*)d_ws;
    unsigned short* xb = (unsigned short*)(ws);
    unsigned short* XP = (unsigned short*)(ws + 16777216);
    unsigned short* H0 = (unsigned short*)(ws + 16777216 + 67108864);
    unsigned short* H1 = (unsigned short*)(ws + 16777216 + 2 * 67108864);

    cvt_kernel<<<8192, 256, 0, stream>>>(x, xb, BB * TT * 64 / 4);

    gemm_xp<64, 128, 0><<<2048, 256, 0, stream>>>(xb, Wx1, b1, XP);
    rec_cp<128><<<32, 256, 0, stream>>>(XP, Wh1, H0);

    gemm_xp<128, 256, 1><<<2048, 256, 0, stream>>>(H0, Wx2, b2, XP);
    rec_cp<256><<<32, 256, 0, stream>>>(XP, Wh2, H1);

    gemm_xp<256, 128, 1><<<2048, 256, 0, stream>>>(H1, Wx3, b3, XP);
    rec_cp<128><<<32, 256, 0, stream>>>(XP, Wh3, H0);

    gemm_xp<128, 64, 1><<<2048, 256, 0, stream>>>(H0, Wx4, b4, XP);
    rec_cp<64><<<32, 256, 0, stream>>>(XP, Wh4, H1);

    dense_kernel<<<32, 256, 0, stream>>>(H1, Wd, bd, out);
}

// Round 8
// 791.379 us; speedup vs baseline: 1.3545x; 1.1250x over previous
//
#include <hip/hip_runtime.h>
#include <hip/hip_bf16.h>

#define BB 512
#define TT 256

typedef __attribute__((ext_vector_type(8))) short bf16x8;
typedef __attribute__((ext_vector_type(4))) float f32x4;

__device__ __forceinline__ unsigned short f2b(float f) {
    union { float f; unsigned u; } v; v.f = f;
    unsigned r = v.u + 0x7FFFu + ((v.u >> 16) & 1u);
    return (unsigned short)(r >> 16);
}
__device__ __forceinline__ float b2f(unsigned short h) {
    union { unsigned u; float f; } v; v.u = ((unsigned)h) << 16;
    return v.f;
}
// packed f32x2 -> bf16x2 (v_cvt_pk_bf16_f32, RNE — bit-compatible with f2b)
__device__ __forceinline__ ushort2 pk2(float a, float b) {
    __hip_bfloat162 h = __float22bfloat162_rn(float2{a, b});
    union { __hip_bfloat162 h; ushort2 u; } v; v.h = h; return v.u;
}

// ---------------- fp32 -> bf16 convert (x input, linear layout) ----------------
__global__ __launch_bounds__(256) void cvt_kernel(const float* __restrict__ x,
                                                  unsigned short* __restrict__ xb, int n4) {
    int i = blockIdx.x * 256 + threadIdx.x;
    if (i >= n4) return;
    float4 v = reinterpret_cast<const float4*>(x)[i];
    ushort2 lo = pk2(v.x, v.y), hi = pk2(v.z, v.w);
    ushort4 o; o.x = lo.x; o.y = lo.y; o.z = hi.x; o.w = hi.y;
    reinterpret_cast<ushort4*>(xb)[i] = o;
}

// ---------------- input-projection GEMM (operand-swapped) ----------------
// D = W^T · x^T. XP out tile (s,t,ntg) at ((s*TT+t)*(N/16)+ntg)*256, elem
// lane*4+reg = (batch l15, col ntg*16+quad*4+reg).
// TILED=0: A is linear [b][t][k] bf16 (layer-1 x). TILED=1: A is tile-layout
// (previous rec output): fragment = two b64 loads 128B apart, coalesced.
template<int K, int N, int TILED>
__global__ __launch_bounds__(256, 2) void gemm_xp(const unsigned short* __restrict__ A,
                                                  const float* __restrict__ W,
                                                  const float* __restrict__ bias,
                                                  unsigned short* __restrict__ XP) {
    constexpr int NT = N / 64;
    constexpr int KC = K / 32;
    __shared__ unsigned short WT[N * K];
    const int tid = threadIdx.x;
    for (int idx = tid; idx < K * N; idx += 256) {
        int k = idx / N, n = idx % N;
        int ch = k >> 3;
        WT[n * K + (((ch ^ (n & 7)) << 3) | (k & 7))] = f2b(W[idx]);
    }
    __syncthreads();
    const int s   = blockIdx.x >> 6;
    const int t4  = blockIdx.x & 63;
    const int w   = tid >> 6;
    const int lane = tid & 63;
    const int l15 = lane & 15;
    const int quad = lane >> 4;

    f32x4 acc[4][NT];
#pragma unroll
    for (int mt = 0; mt < 4; ++mt)
#pragma unroll
        for (int nt = 0; nt < NT; ++nt) acc[mt][nt] = (f32x4)(0.0f);

#pragma unroll
    for (int kc = 0; kc < KC; ++kc) {
        bf16x8 bfr[NT];
        const int ch = kc * 4 + quad;
#pragma unroll
        for (int nt = 0; nt < NT; ++nt) {
            int n = w * (N / 4) + nt * 16 + l15;
            bfr[nt] = *reinterpret_cast<const bf16x8*>(&WT[n * K + ((ch ^ (n & 7)) << 3)]);
        }
#pragma unroll
        for (int mt = 0; mt < 4; ++mt) {
            int t = t4 * 4 + mt;
            bf16x8 bf;
            if (TILED) {
                const unsigned short* tp =
                    &A[(((size_t)(s * TT + t) * (K / 16)) + kc * 2 + (quad >> 1)) * 256];
                int e = ((quad & 1) * 32 + l15) * 4;
                union { ushort4 u4[2]; bf16x8 v; } u;
                u.u4[0] = *reinterpret_cast<const ushort4*>(&tp[e]);
                u.u4[1] = *reinterpret_cast<const ushort4*>(&tp[e + 64]);
                bf = u.v;
            } else {
                int row = (s * 16 + l15) * TT + t;
                bf = *reinterpret_cast<const bf16x8*>(&A[(size_t)row * K + kc * 32 + quad * 8]);
            }
#pragma unroll
            for (int nt = 0; nt < NT; ++nt)
                acc[mt][nt] = __builtin_amdgcn_mfma_f32_16x16x32_bf16(bfr[nt], bf, acc[mt][nt], 0, 0, 0);
        }
    }
#pragma unroll
    for (int mt = 0; mt < 4; ++mt) {
        int t = t4 * 4 + mt;
#pragma unroll
        for (int nt = 0; nt < NT; ++nt) {
            int ntg = w * NT + nt;
            float4 bv = reinterpret_cast<const float4*>(bias)[ntg * 4 + quad];
            size_t base = ((size_t)(s * TT + t) * (N / 16) + ntg) * 256;
            ushort2 lo = pk2(acc[mt][nt][0] + bv.x, acc[mt][nt][1] + bv.y);
            ushort2 hi = pk2(acc[mt][nt][2] + bv.z, acc[mt][nt][3] + bv.w);
            ushort4 o; o.x = lo.x; o.y = lo.y; o.z = hi.x; o.w = hi.y;
            *reinterpret_cast<ushort4*>(&XP[base + (size_t)lane * 4]) = o;
        }
    }
}

// ---------------- recurrence: h_t = relu(xp_t + h_{t-1} @ Wh) ----------------
// Col-partitioned, 4 waves, operand-swapped (A = Wh^T in VGPRs, B = h from
// LDS ping-pong). t-loop unrolled by 2 with TWO independent xp register
// buffers (xpA even steps, xpB odd): each buffer is consumed, then reloaded
// for t+2 — NO end-of-step register copy, so the vmcnt wait for a buffer's
// loads lands two steps (~4000 cyc) after issue instead of ~300 (the ring
// copy in rounds 5-7 forced a same-step HBM-latency stall every step).
// Barrier = builtin lgkm-only waitcnt + s_barrier (no vmcnt drain).
template<int H>
__global__ __launch_bounds__(256, 1) void rec_cp(const unsigned short* __restrict__ XP,
                                                 const float* __restrict__ Wh,
                                                 unsigned short* __restrict__ Hout) {
    constexpr int KC = H / 32;
    constexpr int MT = H / 64;
    constexpr int HP = H + 8;
    __shared__ unsigned short hbuf[2][16 * HP];
    const int tid = threadIdx.x;
    const int s = blockIdx.x;
    const int w = tid >> 6;
    const int lane = tid & 63;
    const int l15 = lane & 15;
    const int quad = lane >> 4;
    const int colbase = w * (H / 4);

    bf16x8 wh[KC][MT];
#pragma unroll
    for (int kc = 0; kc < KC; ++kc)
#pragma unroll
        for (int mt = 0; mt < MT; ++mt) {
            int m = colbase + mt * 16 + l15;
#pragma unroll
            for (int j = 0; j < 8; ++j)
                wh[kc][mt][j] = (short)f2b(Wh[(kc * 32 + quad * 8 + j) * H + m]);
        }

    for (int i = tid; i < 16 * HP; i += 256) hbuf[0][i] = 0;
    __syncthreads();

    const unsigned short* XPs = XP + (size_t)s * TT * (H / 16) * 256;

    ushort4 xpA[MT], xpB[MT];
#pragma unroll
    for (int mt = 0; mt < MT; ++mt) {
        xpA[mt] = reinterpret_cast<const ushort4*>(&XPs[(size_t)(w * MT + mt) * 256])[lane];
        xpB[mt] = reinterpret_cast<const ushort4*>(&XPs[(size_t)((H / 16) + w * MT + mt) * 256])[lane];
    }

#define REC_STEP(TVAL, XPBUF, HRI, HWI)                                                      \
    {                                                                                        \
        const int t_ = (TVAL);                                                               \
        const unsigned short* hr = hbuf[HRI];                                                \
        unsigned short* hw = hbuf[HWI];                                                      \
        bf16x8 af[KC];                                                                       \
        _Pragma("unroll")                                                                    \
        for (int kc = 0; kc < KC; ++kc)                                                      \
            af[kc] = *reinterpret_cast<const bf16x8*>(&hr[l15 * HP + kc * 32 + quad * 8]);   \
        f32x4 acc[MT];                                                                       \
        _Pragma("unroll")                                                                    \
        for (int mt = 0; mt < MT; ++mt) {                                                    \
            acc[mt][0] = b2f(XPBUF[mt].x);                                                   \
            acc[mt][1] = b2f(XPBUF[mt].y);                                                   \
            acc[mt][2] = b2f(XPBUF[mt].z);                                                   \
            acc[mt][3] = b2f(XPBUF[mt].w);                                                   \
        }                                                                                    \
        if (t_ + 2 < TT) {                                                                   \
            _Pragma("unroll")                                                                \
            for (int mt = 0; mt < MT; ++mt)                                                  \
                XPBUF[mt] = reinterpret_cast<const ushort4*>(                                \
                    &XPs[((size_t)(t_ + 2) * (H / 16) + (w * MT + mt)) * 256])[lane];        \
        }                                                                                    \
        _Pragma("unroll")                                                                    \
        for (int kc = 0; kc < KC; ++kc)                                                      \
            _Pragma("unroll")                                                                \
            for (int mt = 0; mt < MT; ++mt)                                                  \
                acc[mt] = __builtin_amdgcn_mfma_f32_16x16x32_bf16(wh[kc][mt], af[kc],        \
                                                                  acc[mt], 0, 0, 0);        \
        _Pragma("unroll")                                                                    \
        for (int mt = 0; mt < MT; ++mt) {                                                    \
            ushort2 lo = pk2(fmaxf(acc[mt][0], 0.f), fmaxf(acc[mt][1], 0.f));                \
            ushort2 hi = pk2(fmaxf(acc[mt][2], 0.f), fmaxf(acc[mt][3], 0.f));                \
            ushort4 o; o.x = lo.x; o.y = lo.y; o.z = hi.x; o.w = hi.y;                       \
            *reinterpret_cast<ushort4*>(&hw[l15 * HP + colbase + mt * 16 + quad * 4]) = o;   \
            size_t gb = (((size_t)(s * TT + t_)) * (H / 16) + w * MT + mt) * 256;            \
            *reinterpret_cast<ushort4*>(&Hout[gb + (size_t)lane * 4]) = o;                   \
        }                                                                                    \
        __builtin_amdgcn_s_waitcnt(0xC07F);                                                  \
        __builtin_amdgcn_s_barrier();                                                        \
    }

#pragma unroll 1
    for (int t = 0; t < TT; t += 2) {
        REC_STEP(t, xpA, 0, 1)
        REC_STEP(t + 1, xpB, 1, 0)
    }
#undef REC_STEP
}

// ---------------- final dense: out[b] = flat[b,:] . Wd + bd ----------------
// H1 is tile-layout (H=64): block per batch-slice s; thread tid <-> tile elem
// tid = (q4*16+l15)*4+r, i.e. (b = s*16+l15, c = q4*4+r). Coalesced reads.
__global__ __launch_bounds__(256) void dense_kernel(const unsigned short* __restrict__ Ht,
                                                    const float* __restrict__ Wd,
                                                    const float* __restrict__ bd,
                                                    float* __restrict__ out) {
    __shared__ float red[16][17];
    const int s = blockIdx.x;
    const int tid = threadIdx.x;
    const int q4 = tid >> 6, l15 = (tid >> 2) & 15, r = tid & 3;
    const int c = q4 * 4 + r;
    float acc = 0.f;
    for (int t = 0; t < TT; ++t) {
        const unsigned short* base = &Ht[((size_t)(s * TT + t) * 4) * 256];
#pragma unroll
        for (int kt = 0; kt < 4; ++kt)
            acc += b2f(base[kt * 256 + tid]) * Wd[t * 64 + kt * 16 + c];
    }
    red[l15][q4 * 4 + r] = acc;
    __syncthreads();
    if (tid < 16) {
        float sum = 0.f;
#pragma unroll
        for (int j = 0; j < 16; ++j) sum += red[tid][j];
        out[s * 16 + tid] = sum + bd[0];
    }
}

extern "C" void kernel_launch(void* const* d_in, const int* in_sizes, int n_in,
                              void* d_out, int out_size, void* d_ws, size_t ws_size,
                              hipStream_t stream) {
    (void)in_sizes; (void)n_in; (void)out_size; (void)ws_size;
    const float* x   = (const float*)d_in[0];
    const float* Wx1 = (const float*)d_in[1];
    const float* Wh1 = (const float*)d_in[2];
    const float* b1  = (const float*)d_in[3];
    const float* Wx2 = (const float*)d_in[4];
    const float* Wh2 = (const float*)d_in[5];
    const float* b2  = (const float*)d_in[6];
    const float* Wx3 = (const float*)d_in[7];
    const float* Wh3 = (const float*)d_in[8];
    const float* b3  = (const float*)d_in[9];
    const float* Wx4 = (const float*)d_in[10];
    const float* Wh4 = (const float*)d_in[11];
    const float* b4  = (const float*)d_in[12];
    const float* Wd  = (const float*)d_in[13];
    const float* bd  = (const float*)d_in[14];
    float* out = (float*)d_out;

    char* ws = (char*)d_ws;
    unsigned short* xb = (unsigned short*)(ws);
    unsigned short* XP = (unsigned short*)(ws + 16777216);
    unsigned short* H0 = (unsigned short*)(ws + 16777216 + 67108864);
    unsigned short* H1 = (unsigned short*)(ws + 16777216 + 2 * 67108864);

    cvt_kernel<<<8192, 256, 0, stream>>>(x, xb, BB * TT * 64 / 4);

    gemm_xp<64, 128, 0><<<2048, 256, 0, stream>>>(xb, Wx1, b1, XP);
    rec_cp<128><<<32, 256, 0, stream>>>(XP, Wh1, H0);

    gemm_xp<128, 256, 1><<<2048, 256, 0, stream>>>(H0, Wx2, b2, XP);
    rec_cp<256><<<32, 256, 0, stream>>>(XP, Wh2, H1);

    gemm_xp<256, 128, 1><<<2048, 256, 0, stream>>>(H1, Wx3, b3, XP);
    rec_cp<128><<<32, 256, 0, stream>>>(XP, Wh3, H0);

    gemm_xp<128, 64, 1><<<2048, 256, 0, stream>>>(H0, Wx4, b4, XP);
    rec_cp<64><<<32, 256, 0, stream>>>(XP, Wh4, H1);

    dense_kernel<<<32, 256, 0, stream>>>(H1, Wd, bd, out);
}

// Round 9
// 770.872 us; speedup vs baseline: 1.3905x; 1.0266x over previous
//
#include <hip/hip_runtime.h>
#include <hip/hip_bf16.h>

#define BB 512
#define TT 256

typedef __attribute__((ext_vector_type(8))) short bf16x8;
typedef __attribute__((ext_vector_type(4))) float f32x4;

__device__ __forceinline__ unsigned short f2b(float f) {
    union { float f; unsigned u; } v; v.f = f;
    unsigned r = v.u + 0x7FFFu + ((v.u >> 16) & 1u);
    return (unsigned short)(r >> 16);
}
__device__ __forceinline__ float b2f(unsigned short h) {
    union { unsigned u; float f; } v; v.u = ((unsigned)h) << 16;
    return v.f;
}
// packed f32x2 -> bf16x2 (v_cvt_pk_bf16_f32, RNE — bit-compatible with f2b)
__device__ __forceinline__ ushort2 pk2(float a, float b) {
    __hip_bfloat162 h = __float22bfloat162_rn(float2{a, b});
    union { __hip_bfloat162 h; ushort2 u; } v; v.h = h; return v.u;
}

// ---------------- fp32 -> bf16 convert (x input, linear layout) ----------------
__global__ __launch_bounds__(256) void cvt_kernel(const float* __restrict__ x,
                                                  unsigned short* __restrict__ xb, int n4) {
    int i = blockIdx.x * 256 + threadIdx.x;
    if (i >= n4) return;
    float4 v = reinterpret_cast<const float4*>(x)[i];
    ushort2 lo = pk2(v.x, v.y), hi = pk2(v.z, v.w);
    ushort4 o; o.x = lo.x; o.y = lo.y; o.z = hi.x; o.w = hi.y;
    reinterpret_cast<ushort4*>(xb)[i] = o;
}

// ---------------- input-projection GEMM (operand-swapped) ----------------
// D = W^T · x^T. XP out tile (s,t,ntg) at ((s*TT+t)*(N/16)+ntg)*256, elem
// lane*4+reg = (batch l15, col ntg*16+quad*4+reg).
// TILED=0: A is linear [b][t][k] bf16 (layer-1 x). TILED=1: A is tile-layout
// (previous rec output): fragment = two b64 loads 128B apart, coalesced.
template<int K, int N, int TILED>
__global__ __launch_bounds__(256, 2) void gemm_xp(const unsigned short* __restrict__ A,
                                                  const float* __restrict__ W,
                                                  const float* __restrict__ bias,
                                                  unsigned short* __restrict__ XP) {
    constexpr int NT = N / 64;
    constexpr int KC = K / 32;
    __shared__ unsigned short WT[N * K];
    const int tid = threadIdx.x;
    for (int idx = tid; idx < K * N; idx += 256) {
        int k = idx / N, n = idx % N;
        int ch = k >> 3;
        WT[n * K + (((ch ^ (n & 7)) << 3) | (k & 7))] = f2b(W[idx]);
    }
    __syncthreads();
    const int s   = blockIdx.x >> 6;
    const int t4  = blockIdx.x & 63;
    const int w   = tid >> 6;
    const int lane = tid & 63;
    const int l15 = lane & 15;
    const int quad = lane >> 4;

    f32x4 acc[4][NT];
#pragma unroll
    for (int mt = 0; mt < 4; ++mt)
#pragma unroll
        for (int nt = 0; nt < NT; ++nt) acc[mt][nt] = (f32x4)(0.0f);

#pragma unroll
    for (int kc = 0; kc < KC; ++kc) {
        bf16x8 bfr[NT];
        const int ch = kc * 4 + quad;
#pragma unroll
        for (int nt = 0; nt < NT; ++nt) {
            int n = w * (N / 4) + nt * 16 + l15;
            bfr[nt] = *reinterpret_cast<const bf16x8*>(&WT[n * K + ((ch ^ (n & 7)) << 3)]);
        }
#pragma unroll
        for (int mt = 0; mt < 4; ++mt) {
            int t = t4 * 4 + mt;
            bf16x8 bf;
            if (TILED) {
                const unsigned short* tp =
                    &A[(((size_t)(s * TT + t) * (K / 16)) + kc * 2 + (quad >> 1)) * 256];
                int e = ((quad & 1) * 32 + l15) * 4;
                union { ushort4 u4[2]; bf16x8 v; } u;
                u.u4[0] = *reinterpret_cast<const ushort4*>(&tp[e]);
                u.u4[1] = *reinterpret_cast<const ushort4*>(&tp[e + 64]);
                bf = u.v;
            } else {
                int row = (s * 16 + l15) * TT + t;
                bf = *reinterpret_cast<const bf16x8*>(&A[(size_t)row * K + kc * 32 + quad * 8]);
            }
#pragma unroll
            for (int nt = 0; nt < NT; ++nt)
                acc[mt][nt] = __builtin_amdgcn_mfma_f32_16x16x32_bf16(bfr[nt], bf, acc[mt][nt], 0, 0, 0);
        }
    }
#pragma unroll
    for (int mt = 0; mt < 4; ++mt) {
        int t = t4 * 4 + mt;
#pragma unroll
        for (int nt = 0; nt < NT; ++nt) {
            int ntg = w * NT + nt;
            float4 bv = reinterpret_cast<const float4*>(bias)[ntg * 4 + quad];
            size_t base = ((size_t)(s * TT + t) * (N / 16) + ntg) * 256;
            ushort2 lo = pk2(acc[mt][nt][0] + bv.x, acc[mt][nt][1] + bv.y);
            ushort2 hi = pk2(acc[mt][nt][2] + bv.z, acc[mt][nt][3] + bv.w);
            ushort4 o; o.x = lo.x; o.y = lo.y; o.z = hi.x; o.w = hi.y;
            *reinterpret_cast<ushort4*>(&XP[base + (size_t)lane * 4]) = o;
        }
    }
}

// ---------------- recurrence: h_t = relu(xp_t + h_{t-1} @ Wh) ----------------
// Col-partitioned, 4 waves, operand-swapped (A = Wh^T in VGPRs). h lives in
// LDS in B-FRAGMENT-READY layout: addr(b,k) = (k>>3)*128 + b*8 + (k&7) shorts.
//  - af reads: 8 conflict-free ds_read_b128 off ONE addr reg + imm kc*1024B
//  - h writes: packed conflict-free b64 off ONE addr reg + imm mt*512B
// XP loads / Hout stores: strength-reduced per-parity pointers (+= const per
// iteration, accesses at imm offsets) — no per-step 64-bit address rebuilds.
// Two independent xp reg buffers (A=even, B=odd steps) reloaded 2 steps ahead.
// Barrier = builtin lgkm-only waitcnt + s_barrier (no vmcnt drain).
template<int H>
__global__ __launch_bounds__(256, 1) void rec_cp(const unsigned short* __restrict__ XP,
                                                 const float* __restrict__ Wh,
                                                 unsigned short* __restrict__ Hout) {
    constexpr int KC  = H / 32;
    constexpr int MT  = H / 64;
    constexpr int STR = (H / 16) * 256;   // shorts per time-step of XP/Hout
    __shared__ __align__(16) unsigned short hbuf[2][16 * H];
    const int tid = threadIdx.x;
    const int s = blockIdx.x;
    const int w = tid >> 6;
    const int lane = tid & 63;
    const int l15 = lane & 15;
    const int quad = lane >> 4;
    const int colbase = w * (H / 4);

    // one-time: Wh^T A-fragments (fp32 global -> bf16)
    bf16x8 wh[KC][MT];
#pragma unroll
    for (int kc = 0; kc < KC; ++kc)
#pragma unroll
        for (int mt = 0; mt < MT; ++mt) {
            int m = colbase + mt * 16 + l15;
#pragma unroll
            for (int j = 0; j < 8; ++j)
                wh[kc][mt][j] = (short)f2b(Wh[(kc * 32 + quad * 8 + j) * H + m]);
        }

    for (int i = tid; i < 16 * H; i += 256) hbuf[0][i] = 0;
    __syncthreads();

    const unsigned short* XPs = XP + (size_t)s * TT * STR;
    unsigned short* Houts = Hout + (size_t)s * TT * STR;

    // LDS offsets (shorts), constant all steps:
    const int rdo = quad * 128 + l15 * 8;                                        // af base
    const int wro = ((colbase >> 3) + (quad >> 1)) * 128 + l15 * 8 + (quad & 1) * 4;  // h write base
    const unsigned short* hr0 = &hbuf[0][0];
    const unsigned short* hr1 = &hbuf[1][0];
    unsigned short* hw0 = &hbuf[0][0];
    unsigned short* hw1 = &hbuf[1][0];

    // xp regs hold t=0 (A) and t=1 (B); pointers aim at t=2 / t=3.
    ushort4 xpA[MT], xpB[MT];
#pragma unroll
    for (int mt = 0; mt < MT; ++mt) {
        xpA[mt] = *reinterpret_cast<const ushort4*>(&XPs[(w * MT + mt) * 256 + lane * 4]);
        xpB[mt] = *reinterpret_cast<const ushort4*>(&XPs[STR + (w * MT + mt) * 256 + lane * 4]);
    }
    const ushort4* xpp0 = reinterpret_cast<const ushort4*>(&XPs[2 * STR + w * MT * 256 + lane * 4]);
    const ushort4* xpp1 = reinterpret_cast<const ushort4*>(&XPs[3 * STR + w * MT * 256 + lane * 4]);
    ushort4* outp0 = reinterpret_cast<ushort4*>(&Houts[w * MT * 256 + lane * 4]);
    ushort4* outp1 = reinterpret_cast<ushort4*>(&Houts[STR + w * MT * 256 + lane * 4]);

#define REC_STEP(T_, XPBUF, XPP, HRP, HWP, OUTP)                                   \
    {                                                                              \
        bf16x8 af[KC];                                                             \
        _Pragma("unroll")                                                          \
        for (int kc = 0; kc < KC; ++kc)                                            \
            af[kc] = *reinterpret_cast<const bf16x8*>(&HRP[rdo + kc * 512]);       \
        f32x4 acc[MT];                                                             \
        _Pragma("unroll")                                                          \
        for (int mt = 0; mt < MT; ++mt) {                                          \
            acc[mt][0] = b2f(XPBUF[mt].x);                                         \
            acc[mt][1] = b2f(XPBUF[mt].y);                                         \
            acc[mt][2] = b2f(XPBUF[mt].z);                                         \
            acc[mt][3] = b2f(XPBUF[mt].w);                                         \
        }                                                                          \
        if ((T_) + 2 < TT) {                                                       \
            _Pragma("unroll")                                                      \
            for (int mt = 0; mt < MT; ++mt) XPBUF[mt] = XPP[mt * 64];              \
            XPP += STR / 2;                                                        \
        }                                                                          \
        _Pragma("unroll")                                                          \
        for (int kc = 0; kc < KC; ++kc)                                            \
            _Pragma("unroll")                                                      \
            for (int mt = 0; mt < MT; ++mt)                                        \
                acc[mt] = __builtin_amdgcn_mfma_f32_16x16x32_bf16(wh[kc][mt],      \
                                                    af[kc], acc[mt], 0, 0, 0);     \
        _Pragma("unroll")                                                          \
        for (int mt = 0; mt < MT; ++mt) {                                          \
            ushort2 lo = pk2(fmaxf(acc[mt][0], 0.f), fmaxf(acc[mt][1], 0.f));      \
            ushort2 hi = pk2(fmaxf(acc[mt][2], 0.f), fmaxf(acc[mt][3], 0.f));      \
            ushort4 o; o.x = lo.x; o.y = lo.y; o.z = hi.x; o.w = hi.y;             \
            *reinterpret_cast<ushort4*>(&HWP[wro + mt * 256]) = o;                 \
            OUTP[mt * 64] = o;                                                     \
        }                                                                          \
        OUTP += STR / 2;                                                           \
        __builtin_amdgcn_s_waitcnt(0xC07F);                                        \
        __builtin_amdgcn_s_barrier();                                              \
    }

#pragma unroll 1
    for (int t = 0; t < TT; t += 2) {
        REC_STEP(t, xpA, xpp0, hr0, hw1, outp0)
        REC_STEP(t + 1, xpB, xpp1, hr1, hw0, outp1)
    }
#undef REC_STEP
}

// ---------------- final dense: out[b] = flat[b,:] . Wd + bd ----------------
// H1 is tile-layout (H=64): block per batch-slice s; thread tid <-> tile elem
// tid = (q4*16+l15)*4+r, i.e. (b = s*16+l15, c = q4*4+r). Coalesced reads.
__global__ __launch_bounds__(256) void dense_kernel(const unsigned short* __restrict__ Ht,
                                                    const float* __restrict__ Wd,
                                                    const float* __restrict__ bd,
                                                    float* __restrict__ out) {
    __shared__ float red[16][17];
    const int s = blockIdx.x;
    const int tid = threadIdx.x;
    const int q4 = tid >> 6, l15 = (tid >> 2) & 15, r = tid & 3;
    const int c = q4 * 4 + r;
    float acc = 0.f;
    for (int t = 0; t < TT; ++t) {
        const unsigned short* base = &Ht[((size_t)(s * TT + t) * 4) * 256];
#pragma unroll
        for (int kt = 0; kt < 4; ++kt)
            acc += b2f(base[kt * 256 + tid]) * Wd[t * 64 + kt * 16 + c];
    }
    red[l15][q4 * 4 + r] = acc;
    __syncthreads();
    if (tid < 16) {
        float sum = 0.f;
#pragma unroll
        for (int j = 0; j < 16; ++j) sum += red[tid][j];
        out[s * 16 + tid] = sum + bd[0];
    }
}

extern "C" void kernel_launch(void* const* d_in, const int* in_sizes, int n_in,
                              void* d_out, int out_size, void* d_ws, size_t ws_size,
                              hipStream_t stream) {
    (void)in_sizes; (void)n_in; (void)out_size; (void)ws_size;
    const float* x   = (const float*)d_in[0];
    const float* Wx1 = (const float*)d_in[1];
    const float* Wh1 = (const float*)d_in[2];
    const float* b1  = (const float*)d_in[3];
    const float* Wx2 = (const float*)d_in[4];
    const float* Wh2 = (const float*)d_in[5];
    const float* b2  = (const float*)d_in[6];
    const float* Wx3 = (const float*)d_in[7];
    const float* Wh3 = (const float*)d_in[8];
    const float* b3  = (const float*)d_in[9];
    const float* Wx4 = (const float*)d_in[10];
    const float* Wh4 = (const float*)d_in[11];
    const float* b4  = (const float*)d_in[12];
    const float* Wd  = (const float*)d_in[13];
    const float* bd  = (const float*)d_in[14];
    float* out = (float*)d_out;

    char* ws = (char*)d_ws;
    unsigned short* xb = (unsigned short*)(ws);
    unsigned short* XP = (unsigned short*)(ws + 16777216);
    unsigned short* H0 = (unsigned short*)(ws + 16777216 + 67108864);
    unsigned short* H1 = (unsigned short*)(ws + 16777216 + 2 * 67108864);

    cvt_kernel<<<8192, 256, 0, stream>>>(x, xb, BB * TT * 64 / 4);

    gemm_xp<64, 128, 0><<<2048, 256, 0, stream>>>(xb, Wx1, b1, XP);
    rec_cp<128><<<32, 256, 0, stream>>>(XP, Wh1, H0);

    gemm_xp<128, 256, 1><<<2048, 256, 0, stream>>>(H0, Wx2, b2, XP);
    rec_cp<256><<<32, 256, 0, stream>>>(XP, Wh2, H1);

    gemm_xp<256, 128, 1><<<2048, 256, 0, stream>>>(H1, Wx3, b3, XP);
    rec_cp<128><<<32, 256, 0, stream>>>(XP, Wh3, H0);

    gemm_xp<128, 64, 1><<<2048, 256, 0, stream>>>(H0, Wx4, b4, XP);
    rec_cp<64><<<32, 256, 0, stream>>>(XP, Wh4, H1);

    dense_kernel<<<32, 256, 0, stream>>>(H1, Wd, bd, out);
}